// Round 5
// baseline (114.776 us; speedup 1.0000x reference)
//
#include <hip/hip_runtime.h>

#define NBDT_BATCH 16384
#define NBDT_C 1024

typedef float f4 __attribute__((ext_vector_type(4)));  // native vector for nontemporal builtins

// sigmoid(x) = 1/(1+exp(-x)); v_exp + v_rcp, ~1 ulp each.
__device__ __forceinline__ float fast_sigmoid(float x) {
    return __builtin_amdgcn_rcpf(1.0f + __expf(-x));
}

// Two rows per wave. For each row, lane i owns leaves
// { k*256 + 4i + j : k=0..3, j=0..3 } -> every global access is a perfectly
// coalesced lane-contiguous dwordx4. 8 independent butterfly chains per wave
// (2 rows x 4 quadrants) double memory-level parallelism and hide the
// ~30-cycle latency of each of the 6 dependent shfl_xor stages.
// Nontemporal hints: both streams are single-pass.
__global__ __launch_bounds__(256) void nbdt_kernel(const float* __restrict__ x,
                                                   float* __restrict__ y) {
    const int wid  = (blockIdx.x * 256 + threadIdx.x) >> 6;  // wave id
    const int lane = threadIdx.x & 63;
    const size_t base = (size_t)(2 * wid) * NBDT_C + (size_t)lane * 4;

    f4 v[2][4];
#pragma unroll
    for (int r = 0; r < 2; ++r)
#pragma unroll
        for (int k = 0; k < 4; ++k)
            v[r][k] = __builtin_nontemporal_load(
                reinterpret_cast<const f4*>(x + base + r * NBDT_C + k * 256));

    float sigA[2][4], sigB[2][4], sig2[2][4], pk[2][4], s256[2][4];
#pragma unroll
    for (int r = 0; r < 2; ++r) {
#pragma unroll
        for (int k = 0; k < 4; ++k) {
            const f4 u = v[r][k];
            sigA[r][k] = fast_sigmoid(u.x - u.y);
            sigB[r][k] = fast_sigmoid(u.z - u.w);
            const float s2a = u.x + u.y;
            const float s2b = u.z + u.w;
            sig2[r][k] = fast_sigmoid((s2a - s2b) * 0.5f);

            float acc = s2a + s2b;  // s4
            float t, p;
            t = __shfl_xor(acc, 1);  p  = fast_sigmoid((acc - t) * (1.0f / 4.0f));   acc += t;
            t = __shfl_xor(acc, 2);  p *= fast_sigmoid((acc - t) * (1.0f / 8.0f));   acc += t;
            t = __shfl_xor(acc, 4);  p *= fast_sigmoid((acc - t) * (1.0f / 16.0f));  acc += t;
            t = __shfl_xor(acc, 8);  p *= fast_sigmoid((acc - t) * (1.0f / 32.0f));  acc += t;
            t = __shfl_xor(acc, 16); p *= fast_sigmoid((acc - t) * (1.0f / 64.0f));  acc += t;
            t = __shfl_xor(acc, 32); p *= fast_sigmoid((acc - t) * (1.0f / 128.0f)); acc += t;
            pk[r][k] = p;
            s256[r][k] = acc;
        }
    }

#pragma unroll
    for (int r = 0; r < 2; ++r) {
        const float pTop = fast_sigmoid(
            (s256[r][0] + s256[r][1] - s256[r][2] - s256[r][3]) * (1.0f / 512.0f));
        const float qTop = 1.0f - pTop;
        const float p01 = fast_sigmoid((s256[r][0] - s256[r][1]) * (1.0f / 256.0f));
        const float p23 = fast_sigmoid((s256[r][2] - s256[r][3]) * (1.0f / 256.0f));
        float P[4];
        P[0] = pTop * p01;  P[1] = pTop - P[0];
        P[2] = qTop * p23;  P[3] = qTop - P[2];

#pragma unroll
        for (int k = 0; k < 4; ++k) {
            const float Pk = P[k] * pk[r][k];
            const float c0 = Pk * sig2[r][k];
            const float c1 = Pk - c0;
            f4 o;
            o.x = c0 * sigA[r][k];
            o.y = c0 - o.x;
            o.z = c1 * sigB[r][k];
            o.w = c1 - o.z;
            __builtin_nontemporal_store(
                o, reinterpret_cast<f4*>(y + base + r * NBDT_C + k * 256));
        }
    }
}

extern "C" void kernel_launch(void* const* d_in, const int* in_sizes, int n_in,
                              void* d_out, int out_size, void* d_ws, size_t ws_size,
                              hipStream_t stream) {
    const float* x = (const float*)d_in[0];
    float* y = (float*)d_out;
    // 16384 rows, 2 rows per wave, 4 waves per 256-thread block -> 2048 blocks.
    dim3 grid(NBDT_BATCH / 8);
    dim3 block(256);
    nbdt_kernel<<<grid, block, 0, stream>>>(x, y);
}

// Round 6
// 109.476 us; speedup vs baseline: 1.0484x; 1.0484x over previous
//
#include <hip/hip_runtime.h>

#define NBDT_BATCH 16384
#define NBDT_C 1024

// sigmoid(x) = 1/(1+exp(-x)); v_exp + v_rcp, ~1 ulp each.
__device__ __forceinline__ float fast_sigmoid(float x) {
    return __builtin_amdgcn_rcpf(1.0f + __expf(-x));
}

// One wave per row. Lane i owns leaves { k*256 + 4i + j : k=0..3, j=0..3 } so
// every global load/store is a perfectly coalesced lane-contiguous dwordx4.
// Best-measured variant (R2 structure): 4096 blocks, cached loads (input is
// L2/L3-warm from the harness restore), register-lean tree.
__global__ __launch_bounds__(256, 8) void nbdt_kernel(const float* __restrict__ x,
                                                      float* __restrict__ y) {
    const int wave = (blockIdx.x * 256 + threadIdx.x) >> 6;
    const int lane = threadIdx.x & 63;
    const size_t rowbase = (size_t)wave * NBDT_C + (size_t)lane * 4;

    float4 v[4];
#pragma unroll
    for (int k = 0; k < 4; ++k)
        v[k] = *reinterpret_cast<const float4*>(x + rowbase + k * 256);

    float sigA[4], sigB[4], sig2[4], pk[4], s256[4];
#pragma unroll
    for (int k = 0; k < 4; ++k) {
        sigA[k] = fast_sigmoid(v[k].x - v[k].y);
        sigB[k] = fast_sigmoid(v[k].z - v[k].w);
        const float s2a = v[k].x + v[k].y;
        const float s2b = v[k].z + v[k].w;
        sig2[k] = fast_sigmoid((s2a - s2b) * 0.5f);

        float acc = s2a + s2b;  // s4
        float t, p;
        t = __shfl_xor(acc, 1);  p  = fast_sigmoid((acc - t) * (1.0f / 4.0f));   acc += t;
        t = __shfl_xor(acc, 2);  p *= fast_sigmoid((acc - t) * (1.0f / 8.0f));   acc += t;
        t = __shfl_xor(acc, 4);  p *= fast_sigmoid((acc - t) * (1.0f / 16.0f));  acc += t;
        t = __shfl_xor(acc, 8);  p *= fast_sigmoid((acc - t) * (1.0f / 32.0f));  acc += t;
        t = __shfl_xor(acc, 16); p *= fast_sigmoid((acc - t) * (1.0f / 64.0f));  acc += t;
        t = __shfl_xor(acc, 32); p *= fast_sigmoid((acc - t) * (1.0f / 128.0f)); acc += t;
        pk[k] = p;
        s256[k] = acc;
    }

    // top two levels (lane-uniform)
    const float pTop = fast_sigmoid((s256[0] + s256[1] - s256[2] - s256[3]) * (1.0f / 512.0f));
    const float qTop = 1.0f - pTop;
    const float p01  = fast_sigmoid((s256[0] - s256[1]) * (1.0f / 256.0f));
    const float p23  = fast_sigmoid((s256[2] - s256[3]) * (1.0f / 256.0f));
    float P[4];
    P[0] = pTop * p01;  P[1] = pTop - P[0];
    P[2] = qTop * p23;  P[3] = qTop - P[2];

#pragma unroll
    for (int k = 0; k < 4; ++k) {
        const float Pk = P[k] * pk[k];
        const float c0 = Pk * sig2[k];   // blk=2 left child
        const float c1 = Pk - c0;        // exact complement
        float4 o;
        o.x = c0 * sigA[k];
        o.y = c0 - o.x;
        o.z = c1 * sigB[k];
        o.w = c1 - o.z;
        *reinterpret_cast<float4*>(y + rowbase + k * 256) = o;
    }
}

extern "C" void kernel_launch(void* const* d_in, const int* in_sizes, int n_in,
                              void* d_out, int out_size, void* d_ws, size_t ws_size,
                              hipStream_t stream) {
    const float* x = (const float*)d_in[0];
    float* y = (float*)d_out;
    // 16384 rows, 1 row per wave, 4 waves per 256-thread block -> 4096 blocks.
    dim3 grid(NBDT_BATCH / 4);
    dim3 block(256);
    nbdt_kernel<<<grid, block, 0, stream>>>(x, y);
}